// Round 4
// baseline (4799.825 us; speedup 1.0000x reference)
//
#include <hip/hip_runtime.h>
#include <hip/hip_fp16.h>

// Sinkhorn OT loss, N=8192, D=128.
// K = exp(-C/eps) in fp8 e4m3 (64 MB), built once by MFMA kmat.
// Per-iteration kernel: 512 blocks x 256 threads; each thread holds its
// 16-row x 32-col fp8 tile of K in REGISTERS (128 VGPRs), so K is read
// ONCE per iteration (pass A: u = mu/(Kv); pass B: column partials of K^T u
// from the same registers). tp partials fp16 (x65536), v fp16.

constexpr int   N      = 8192;
constexpr int   D      = 128;
constexpr float EPSV   = 0.05f;
constexpr int   NITER  = 50;
constexpr float STABV  = 1e-8f;
constexpr float MU     = 1.0f / N;
constexpr float NU     = 1.0f / N;
constexpr float TPSCALE  = 65536.0f;
constexpr float TPINV    = 1.0f / 65536.0f;
constexpr float NEG_LOG2E_OVER_EPS = -1.4426950408889634f / EPSV;
constexpr float NEG_EPS_LN2 = -EPSV * 0.6931471805599453f;

typedef float    f32x2  __attribute__((ext_vector_type(2)));
typedef float    f32x4v __attribute__((ext_vector_type(4)));
typedef _Float16 half4v __attribute__((ext_vector_type(4)));
typedef _Float16 half8v __attribute__((ext_vector_type(8)));

__device__ __forceinline__ void dot4_fp8(unsigned w, const float* vj, float& s) {
    f32x2 lo = __builtin_amdgcn_cvt_pk_f32_fp8((int)w, false);
    f32x2 hi = __builtin_amdgcn_cvt_pk_f32_fp8((int)w, true);
    s += lo[0]*vj[0] + lo[1]*vj[1] + hi[0]*vj[2] + hi[1]*vj[3];
}
__device__ __forceinline__ void acc4_fp8(unsigned w, float ur, float* a) {
    f32x2 lo = __builtin_amdgcn_cvt_pk_f32_fp8((int)w, false);
    f32x2 hi = __builtin_amdgcn_cvt_pk_f32_fp8((int)w, true);
    a[0] += ur*lo[0]; a[1] += ur*lo[1]; a[2] += ur*hi[0]; a[3] += ur*hi[1];
}

// ---------------- init: x2, y2, v=1 (fp16), out=0 ----------------
__global__ __launch_bounds__(256) void init_kernel(
    const float* __restrict__ X, const float* __restrict__ Y,
    float* __restrict__ x2, float* __restrict__ y2,
    __half* __restrict__ v, float* __restrict__ out)
{
    int tid  = threadIdx.x;
    int gtid = blockIdx.x * 256 + tid;
    if (gtid < N) v[gtid] = __float2half(1.0f);
    if (gtid == 0) out[0] = 0.0f;

    int wave = tid >> 6, lane = tid & 63;
    int row = blockIdx.x * 4 + wave;
    const float* src = (row < N) ? (X + (size_t)row * D)
                                 : (Y + (size_t)(row - N) * D);
    float a = src[lane], b = src[lane + 64];
    float s = a * a + b * b;
    #pragma unroll
    for (int off = 32; off > 0; off >>= 1) s += __shfl_down(s, off, 64);
    if (lane == 0) {
        if (row < N) x2[row] = s; else y2[row - N] = s;
    }
}

// ---------------- K matrix: fp16 MFMA GEMM + exp, store fp8 ----------------
__global__ __launch_bounds__(256) void kmat_kernel(
    const float* __restrict__ X, const float* __restrict__ Y,
    const float* __restrict__ x2, const float* __restrict__ y2,
    unsigned char* __restrict__ Km)
{
    __shared__ _Float16 Xs[128 * 128];
    __shared__ _Float16 Ys[128 * 128];
    int t = threadIdx.x;
    int rowBase = blockIdx.y * 128, colBase = blockIdx.x * 128;

    #pragma unroll
    for (int l = 0; l < 16; ++l) {
        int e = l * 256 + t;
        int r = e >> 5, c4 = e & 31;
        int sw = r * 128 + ((((c4 >> 1) ^ (r & 7)) << 3) + (c4 & 1) * 4);
        float4 a = *(const float4*)(X + (size_t)(rowBase + r) * D + c4 * 4);
        float4 b = *(const float4*)(Y + (size_t)(colBase + r) * D + c4 * 4);
        half4v ha = { (_Float16)a.x, (_Float16)a.y, (_Float16)a.z, (_Float16)a.w };
        half4v hb = { (_Float16)b.x, (_Float16)b.y, (_Float16)b.z, (_Float16)b.w };
        *(half4v*)&Xs[sw] = ha;
        *(half4v*)&Ys[sw] = hb;
    }
    __syncthreads();

    int wave = t >> 6, lane = t & 63;
    int wr = (wave >> 1) * 64, wc = (wave & 1) * 64;
    int m = lane & 15, quad = lane >> 4;

    f32x4v acc[4][4];
    #pragma unroll
    for (int i = 0; i < 4; ++i)
        #pragma unroll
        for (int j = 0; j < 4; ++j)
            acc[i][j] = (f32x4v){0.f, 0.f, 0.f, 0.f};

    #pragma unroll
    for (int kk = 0; kk < 4; ++kk) {
        half8v af[4], bf[4];
        int uidx = kk * 4 + quad;
        #pragma unroll
        for (int i = 0; i < 4; ++i) {
            int Ra = wr + i * 16 + m;
            int Rb = wc + i * 16 + m;
            af[i] = *(const half8v*)&Xs[Ra * 128 + ((uidx ^ (Ra & 7)) << 3)];
            bf[i] = *(const half8v*)&Ys[Rb * 128 + ((uidx ^ (Rb & 7)) << 3)];
        }
        #pragma unroll
        for (int i = 0; i < 4; ++i)
            #pragma unroll
            for (int j = 0; j < 4; ++j)
                acc[i][j] = __builtin_amdgcn_mfma_f32_16x16x32_f16(af[i], bf[j], acc[i][j], 0, 0, 0);
    }

    float y2c[4];
    #pragma unroll
    for (int j = 0; j < 4; ++j) y2c[j] = y2[colBase + wc + j * 16 + m];

    #pragma unroll
    for (int i = 0; i < 4; ++i) {
        #pragma unroll
        for (int rr = 0; rr < 4; ++rr) {
            int row = rowBase + wr + i * 16 + quad * 4 + rr;
            float xs = x2[row];
            size_t ro = (size_t)row * N + colBase + wc + m;
            #pragma unroll
            for (int j = 0; j < 4; j += 2) {
                float c0 = fmaxf(xs + y2c[j]     - 2.f * acc[i][j][rr],     0.f);
                float c1 = fmaxf(xs + y2c[j + 1] - 2.f * acc[i][j + 1][rr], 0.f);
                float k0 = exp2f(c0 * NEG_LOG2E_OVER_EPS);
                float k1 = exp2f(c1 * NEG_LOG2E_OVER_EPS);
                unsigned p = (unsigned)__builtin_amdgcn_cvt_pk_fp8_f32(k0, k1, 0, false);
                Km[ro + j * 16]      = (unsigned char)(p & 0xff);
                Km[ro + j * 16 + 16] = (unsigned char)((p >> 8) & 0xff);
            }
        }
    }
}

// ---------------- fused iteration, register-resident K tile ----------------
// Block b owns rows [16b,16b+16); thread t owns cols [16t,+16) and [4096+16t,+16).
// K read from memory ONCE: pass A (u) and pass B (K^T u partials) both from regs.
__global__ __launch_bounds__(256, 2) void iter_kernel(
    const unsigned char* __restrict__ Km, const __half* __restrict__ v,
    float* __restrict__ u, __half* __restrict__ tp)
{
    __shared__ float us[16];
    __shared__ float red[4][16];

    int t = threadIdx.x, wave = t >> 6, lane = t & 63;
    int b = blockIdx.x;
    int r0 = b * 16;

    // v fragment: 32 cols
    float vj[32];
    {
        const __half2* vp0 = (const __half2*)(v + t * 16);
        const __half2* vp1 = (const __half2*)(v + 4096 + t * 16);
        #pragma unroll
        for (int i = 0; i < 8; ++i) {
            float2 f0 = __half22float2(vp0[i]);
            float2 f1 = __half22float2(vp1[i]);
            vj[2*i]    = f0.x; vj[2*i+1]    = f0.y;
            vj[16+2*i] = f1.x; vj[16+2*i+1] = f1.y;
        }
    }

    // ---- load K tile into registers + pass A row dots ----
    uint4 kreg[16][2];
    const unsigned char* kb = Km + (size_t)r0 * N + t * 16;
    float ps[16];
    #pragma unroll
    for (int r = 0; r < 16; ++r) {
        kreg[r][0] = *(const uint4*)(kb + (size_t)r * N);
        kreg[r][1] = *(const uint4*)(kb + (size_t)r * N + 4096);
        float s = 0.f;
        dot4_fp8(kreg[r][0].x, vj + 0,  s);
        dot4_fp8(kreg[r][0].y, vj + 4,  s);
        dot4_fp8(kreg[r][0].z, vj + 8,  s);
        dot4_fp8(kreg[r][0].w, vj + 12, s);
        dot4_fp8(kreg[r][1].x, vj + 16, s);
        dot4_fp8(kreg[r][1].y, vj + 20, s);
        dot4_fp8(kreg[r][1].z, vj + 24, s);
        dot4_fp8(kreg[r][1].w, vj + 28, s);
        ps[r] = s;
    }
    #pragma unroll
    for (int r = 0; r < 16; ++r) {
        float s = ps[r];
        #pragma unroll
        for (int off = 32; off > 0; off >>= 1) s += __shfl_down(s, off, 64);
        if (lane == 0) red[wave][r] = s;
    }
    __syncthreads();
    if (t < 16) {
        float ur = MU / (red[0][t] + red[1][t] + red[2][t] + red[3][t] + STABV);
        us[t] = ur;
        u[r0 + t] = ur;
    }
    __syncthreads();

    // ---- pass B: column partials from register K ----
    float ca[32];
    #pragma unroll
    for (int q = 0; q < 32; ++q) ca[q] = 0.f;
    #pragma unroll
    for (int r = 0; r < 16; ++r) {
        float ur = us[r];
        acc4_fp8(kreg[r][0].x, ur, ca + 0);
        acc4_fp8(kreg[r][0].y, ur, ca + 4);
        acc4_fp8(kreg[r][0].z, ur, ca + 8);
        acc4_fp8(kreg[r][0].w, ur, ca + 12);
        acc4_fp8(kreg[r][1].x, ur, ca + 16);
        acc4_fp8(kreg[r][1].y, ur, ca + 20);
        acc4_fp8(kreg[r][1].z, ur, ca + 24);
        acc4_fp8(kreg[r][1].w, ur, ca + 28);
    }
    {
        union { __half2 h2[8]; uint4 q[2]; } pk;
        #pragma unroll
        for (int i = 0; i < 8; ++i)
            pk.h2[i] = __floats2half2_rn(ca[2*i] * TPSCALE, ca[2*i+1] * TPSCALE);
        uint4* dst = (uint4*)(tp + (size_t)b * N + t * 16);
        dst[0] = pk.q[0]; dst[1] = pk.q[1];
        #pragma unroll
        for (int i = 0; i < 8; ++i)
            pk.h2[i] = __floats2half2_rn(ca[16+2*i] * TPSCALE, ca[16+2*i+1] * TPSCALE);
        uint4* dst2 = (uint4*)(tp + (size_t)b * N + 4096 + t * 16);
        dst2[0] = pk.q[0]; dst2[1] = pk.q[1];
    }
}

// ---------------- v = nu / (sum of 512 fp16 partials + stab) ----------------
__global__ __launch_bounds__(256) void colfin_kernel(
    const __half* __restrict__ tp, __half* __restrict__ v)
{
    int t = threadIdx.x;
    int c2 = blockIdx.x * 32 + (t & 31);    // half2 column index; grid 128
    int g  = t >> 5;                         // 8 chunk groups
    const __half2* tp2 = (const __half2*)tp;
    float sx = 0.f, sy = 0.f;
    #pragma unroll 4
    for (int k = 0; k < 64; ++k) {
        float2 f = __half22float2(tp2[(size_t)(g * 64 + k) * (N / 2) + c2]);
        sx += f.x; sy += f.y;
    }
    __shared__ float redx[8][33], redy[8][33];
    redx[g][t & 31] = sx; redy[g][t & 31] = sy;
    __syncthreads();
    if (t < 32) {
        float ax = 0.f, ay = 0.f;
        #pragma unroll
        for (int gg = 0; gg < 8; ++gg) { ax += redx[gg][t]; ay += redy[gg][t]; }
        float vx = NU / (ax * TPINV + STABV);
        float vy = NU / (ay * TPINV + STABV);
        ((__half2*)v)[blockIdx.x * 32 + t] = __floats2half2_rn(vx, vy);
    }
}

// ---------------- loss = sum u_i K_ij v_j * (-eps ln K_ij) ----------------
__global__ __launch_bounds__(256) void loss_kernel(
    const unsigned char* __restrict__ Km, const float* __restrict__ u,
    const __half* __restrict__ vv, float* __restrict__ out)
{
    int t = threadIdx.x;
    int j0 = blockIdx.x * 2048 + t * 8;     // grid (4, 128)
    int i0 = blockIdx.y * 64;
    float vj[8];
    {
        const __half2* vp = (const __half2*)(vv + j0);
        #pragma unroll
        for (int i = 0; i < 4; ++i) {
            float2 f = __half22float2(vp[i]);
            vj[2*i] = f.x; vj[2*i+1] = f.y;
        }
    }
    float a[8] = {};
    for (int i = 0; i < 64; ++i) {
        float ui = u[i0 + i];
        uint2 raw = *(const uint2*)(Km + (size_t)(i0 + i) * N + j0);
        float k[8];
        f32x2 lo = __builtin_amdgcn_cvt_pk_f32_fp8((int)raw.x, false);
        f32x2 hi = __builtin_amdgcn_cvt_pk_f32_fp8((int)raw.x, true);
        k[0]=lo[0]; k[1]=lo[1]; k[2]=hi[0]; k[3]=hi[1];
        lo = __builtin_amdgcn_cvt_pk_f32_fp8((int)raw.y, false);
        hi = __builtin_amdgcn_cvt_pk_f32_fp8((int)raw.y, true);
        k[4]=lo[0]; k[5]=lo[1]; k[6]=hi[0]; k[7]=hi[1];
        #pragma unroll
        for (int q = 0; q < 8; ++q) {
            float kk = fmaxf(k[q], 6e-8f);
            a[q] += ui * kk * __log2f(kk);
        }
    }
    float s = 0.f;
    #pragma unroll
    for (int q = 0; q < 8; ++q) s += a[q] * vj[q];
    s *= NEG_EPS_LN2;
    #pragma unroll
    for (int off = 32; off > 0; off >>= 1) s += __shfl_down(s, off, 64);
    __shared__ float ws[4];
    if ((t & 63) == 0) ws[t >> 6] = s;
    __syncthreads();
    if (t == 0) atomicAdd(out, ws[0] + ws[1] + ws[2] + ws[3]);
}

extern "C" void kernel_launch(void* const* d_in, const int* in_sizes, int n_in,
                              void* d_out, int out_size, void* d_ws, size_t ws_size,
                              hipStream_t stream) {
    const float* X = (const float*)d_in[0];
    const float* Y = (const float*)d_in[1];
    float* out = (float*)d_out;

    char* ws = (char*)d_ws;
    unsigned char* Km = (unsigned char*)ws;
    size_t off = (size_t)N * N;                       // 64 MB fp8
    __half* tp = (__half*)(ws + off); off += (size_t)512 * N * sizeof(__half); // 8 MB
    float* x2 = (float*)(ws + off); off += (size_t)N * 4;
    float* y2 = (float*)(ws + off); off += (size_t)N * 4;
    float* u  = (float*)(ws + off); off += (size_t)N * 4;
    __half* v = (__half*)(ws + off); off += (size_t)N * sizeof(__half);

    init_kernel<<<4096, 256, 0, stream>>>(X, Y, x2, y2, v, out);
    kmat_kernel<<<dim3(N / 128, N / 128), 256, 0, stream>>>(X, Y, x2, y2, Km);
    for (int it = 0; it < NITER; ++it) {
        iter_kernel<<<512, 256, 0, stream>>>(Km, v, u, tp);
        colfin_kernel<<<128, 256, 0, stream>>>(tp, v);
    }
    loss_kernel<<<dim3(4, 128), 256, 0, stream>>>(Km, u, v, out);
}

// Round 5
// 1278.780 us; speedup vs baseline: 3.7534x; 3.7534x over previous
//
#include <hip/hip_runtime.h>
#include <hip/hip_fp16.h>

// Sinkhorn OT loss, N=8192, D=128.
// K = exp(-C/eps) in fp8 e4m3 (64 MB), built once by MFMA kmat.
// iter_kernel: 512 blocks x 256 threads, 16 rows/block processed in 4 chunks
// of 4 rows held in REGISTERS (32 VGPRs/chunk) -- K is read from memory ONCE
// per iteration; pass A (u = mu/(Kv)) and pass B (K^T u partials) both
// consume the same registers. No spill (R4 post-mortem: 128-reg tile spilled).
// tp partials fp16 (x65536), v fp16.

constexpr int   N      = 8192;
constexpr int   D      = 128;
constexpr float EPSV   = 0.05f;
constexpr int   NITER  = 50;
constexpr float STABV  = 1e-8f;
constexpr float MU     = 1.0f / N;
constexpr float NU     = 1.0f / N;
constexpr float TPSCALE  = 65536.0f;
constexpr float TPINV    = 1.0f / 65536.0f;
constexpr float NEG_LOG2E_OVER_EPS = -1.4426950408889634f / EPSV;
constexpr float NEG_EPS_LN2 = -EPSV * 0.6931471805599453f;

typedef float    f32x2  __attribute__((ext_vector_type(2)));
typedef float    f32x4v __attribute__((ext_vector_type(4)));
typedef _Float16 half4v __attribute__((ext_vector_type(4)));
typedef _Float16 half8v __attribute__((ext_vector_type(8)));

__device__ __forceinline__ void dot4_fp8(unsigned w, const float* vj, float& s) {
    f32x2 lo = __builtin_amdgcn_cvt_pk_f32_fp8((int)w, false);
    f32x2 hi = __builtin_amdgcn_cvt_pk_f32_fp8((int)w, true);
    s += lo[0]*vj[0] + lo[1]*vj[1] + hi[0]*vj[2] + hi[1]*vj[3];
}
__device__ __forceinline__ void acc4_fp8(unsigned w, float ur, float* a) {
    f32x2 lo = __builtin_amdgcn_cvt_pk_f32_fp8((int)w, false);
    f32x2 hi = __builtin_amdgcn_cvt_pk_f32_fp8((int)w, true);
    a[0] += ur*lo[0]; a[1] += ur*lo[1]; a[2] += ur*hi[0]; a[3] += ur*hi[1];
}

// ---------------- init: x2, y2, v=1 (fp16), out=0 ----------------
__global__ __launch_bounds__(256) void init_kernel(
    const float* __restrict__ X, const float* __restrict__ Y,
    float* __restrict__ x2, float* __restrict__ y2,
    __half* __restrict__ v, float* __restrict__ out)
{
    int tid  = threadIdx.x;
    int gtid = blockIdx.x * 256 + tid;
    if (gtid < N) v[gtid] = __float2half(1.0f);
    if (gtid == 0) out[0] = 0.0f;

    int wave = tid >> 6, lane = tid & 63;
    int row = blockIdx.x * 4 + wave;
    const float* src = (row < N) ? (X + (size_t)row * D)
                                 : (Y + (size_t)(row - N) * D);
    float a = src[lane], b = src[lane + 64];
    float s = a * a + b * b;
    #pragma unroll
    for (int off = 32; off > 0; off >>= 1) s += __shfl_down(s, off, 64);
    if (lane == 0) {
        if (row < N) x2[row] = s; else y2[row - N] = s;
    }
}

// ---------------- K matrix: fp16 MFMA GEMM + exp, store fp8 ----------------
__global__ __launch_bounds__(256) void kmat_kernel(
    const float* __restrict__ X, const float* __restrict__ Y,
    const float* __restrict__ x2, const float* __restrict__ y2,
    unsigned char* __restrict__ Km)
{
    __shared__ _Float16 Xs[128 * 128];
    __shared__ _Float16 Ys[128 * 128];
    int t = threadIdx.x;
    int rowBase = blockIdx.y * 128, colBase = blockIdx.x * 128;

    #pragma unroll
    for (int l = 0; l < 16; ++l) {
        int e = l * 256 + t;
        int r = e >> 5, c4 = e & 31;
        int sw = r * 128 + ((((c4 >> 1) ^ (r & 7)) << 3) + (c4 & 1) * 4);
        float4 a = *(const float4*)(X + (size_t)(rowBase + r) * D + c4 * 4);
        float4 b = *(const float4*)(Y + (size_t)(colBase + r) * D + c4 * 4);
        half4v ha = { (_Float16)a.x, (_Float16)a.y, (_Float16)a.z, (_Float16)a.w };
        half4v hb = { (_Float16)b.x, (_Float16)b.y, (_Float16)b.z, (_Float16)b.w };
        *(half4v*)&Xs[sw] = ha;
        *(half4v*)&Ys[sw] = hb;
    }
    __syncthreads();

    int wave = t >> 6, lane = t & 63;
    int wr = (wave >> 1) * 64, wc = (wave & 1) * 64;
    int m = lane & 15, quad = lane >> 4;

    f32x4v acc[4][4];
    #pragma unroll
    for (int i = 0; i < 4; ++i)
        #pragma unroll
        for (int j = 0; j < 4; ++j)
            acc[i][j] = (f32x4v){0.f, 0.f, 0.f, 0.f};

    #pragma unroll
    for (int kk = 0; kk < 4; ++kk) {
        half8v af[4], bf[4];
        int uidx = kk * 4 + quad;
        #pragma unroll
        for (int i = 0; i < 4; ++i) {
            int Ra = wr + i * 16 + m;
            int Rb = wc + i * 16 + m;
            af[i] = *(const half8v*)&Xs[Ra * 128 + ((uidx ^ (Ra & 7)) << 3)];
            bf[i] = *(const half8v*)&Ys[Rb * 128 + ((uidx ^ (Rb & 7)) << 3)];
        }
        #pragma unroll
        for (int i = 0; i < 4; ++i)
            #pragma unroll
            for (int j = 0; j < 4; ++j)
                acc[i][j] = __builtin_amdgcn_mfma_f32_16x16x32_f16(af[i], bf[j], acc[i][j], 0, 0, 0);
    }

    float y2c[4];
    #pragma unroll
    for (int j = 0; j < 4; ++j) y2c[j] = y2[colBase + wc + j * 16 + m];

    #pragma unroll
    for (int i = 0; i < 4; ++i) {
        #pragma unroll
        for (int rr = 0; rr < 4; ++rr) {
            int row = rowBase + wr + i * 16 + quad * 4 + rr;
            float xs = x2[row];
            size_t ro = (size_t)row * N + colBase + wc + m;
            #pragma unroll
            for (int j = 0; j < 4; j += 2) {
                float c0 = fmaxf(xs + y2c[j]     - 2.f * acc[i][j][rr],     0.f);
                float c1 = fmaxf(xs + y2c[j + 1] - 2.f * acc[i][j + 1][rr], 0.f);
                float k0 = exp2f(c0 * NEG_LOG2E_OVER_EPS);
                float k1 = exp2f(c1 * NEG_LOG2E_OVER_EPS);
                unsigned p = (unsigned)__builtin_amdgcn_cvt_pk_fp8_f32(k0, k1, 0, false);
                Km[ro + j * 16]      = (unsigned char)(p & 0xff);
                Km[ro + j * 16 + 16] = (unsigned char)((p >> 8) & 0xff);
            }
        }
    }
}

// ---------------- fused iteration, chunked register-resident K ----------------
// Block b owns rows [16b,16b+16) in 4 chunks of 4; thread t owns cols
// [16t,+16) and [4096+16t,+16). Each chunk: load 4 rows into regs (32 VGPRs),
// pass A dots -> u, pass B accumulates ca from same regs. K read once.
__global__ __launch_bounds__(256, 2) void iter_kernel(
    const unsigned char* __restrict__ Km, const __half* __restrict__ v,
    float* __restrict__ u, __half* __restrict__ tp)
{
    __shared__ float red[4][4];

    int t = threadIdx.x, wave = t >> 6, lane = t & 63;
    int b = blockIdx.x;
    int r0 = b * 16;

    // v fragment: 32 cols
    float vj[32];
    {
        const __half2* vp0 = (const __half2*)(v + t * 16);
        const __half2* vp1 = (const __half2*)(v + 4096 + t * 16);
        #pragma unroll
        for (int i = 0; i < 8; ++i) {
            float2 f0 = __half22float2(vp0[i]);
            float2 f1 = __half22float2(vp1[i]);
            vj[2*i]    = f0.x; vj[2*i+1]    = f0.y;
            vj[16+2*i] = f1.x; vj[16+2*i+1] = f1.y;
        }
    }

    const unsigned char* kb = Km + (size_t)r0 * N + t * 16;
    float ca[32];
    #pragma unroll
    for (int q = 0; q < 32; ++q) ca[q] = 0.f;

    for (int c = 0; c < 4; ++c) {
        int rbase = c * 4;
        uint4 k0[4], k1[4];
        #pragma unroll
        for (int r = 0; r < 4; ++r) {
            k0[r] = *(const uint4*)(kb + (size_t)(rbase + r) * N);
            k1[r] = *(const uint4*)(kb + (size_t)(rbase + r) * N + 4096);
        }
        float ps[4];
        #pragma unroll
        for (int r = 0; r < 4; ++r) {
            float s = 0.f;
            dot4_fp8(k0[r].x, vj + 0,  s);
            dot4_fp8(k0[r].y, vj + 4,  s);
            dot4_fp8(k0[r].z, vj + 8,  s);
            dot4_fp8(k0[r].w, vj + 12, s);
            dot4_fp8(k1[r].x, vj + 16, s);
            dot4_fp8(k1[r].y, vj + 20, s);
            dot4_fp8(k1[r].z, vj + 24, s);
            dot4_fp8(k1[r].w, vj + 28, s);
            ps[r] = s;
        }
        #pragma unroll
        for (int r = 0; r < 4; ++r) {
            float s = ps[r];
            #pragma unroll
            for (int off = 32; off > 0; off >>= 1) s += __shfl_down(s, off, 64);
            if (lane == 0) red[wave][r] = s;
        }
        __syncthreads();
        float us4[4];
        #pragma unroll
        for (int r = 0; r < 4; ++r)
            us4[r] = MU / (red[0][r] + red[1][r] + red[2][r] + red[3][r] + STABV);
        if (t < 4) u[r0 + rbase + t] = us4[t];

        #pragma unroll
        for (int r = 0; r < 4; ++r) {
            float ur = us4[r];
            acc4_fp8(k0[r].x, ur, ca + 0);
            acc4_fp8(k0[r].y, ur, ca + 4);
            acc4_fp8(k0[r].z, ur, ca + 8);
            acc4_fp8(k0[r].w, ur, ca + 12);
            acc4_fp8(k1[r].x, ur, ca + 16);
            acc4_fp8(k1[r].y, ur, ca + 20);
            acc4_fp8(k1[r].z, ur, ca + 24);
            acc4_fp8(k1[r].w, ur, ca + 28);
        }
        __syncthreads();   // red reused next chunk
    }

    // write fp16 partials
    union { __half2 h2[8]; uint4 q[2]; } pk;
    #pragma unroll
    for (int i = 0; i < 8; ++i)
        pk.h2[i] = __floats2half2_rn(ca[2*i] * TPSCALE, ca[2*i+1] * TPSCALE);
    uint4* dst = (uint4*)(tp + (size_t)b * N + t * 16);
    dst[0] = pk.q[0]; dst[1] = pk.q[1];
    #pragma unroll
    for (int i = 0; i < 8; ++i)
        pk.h2[i] = __floats2half2_rn(ca[16+2*i] * TPSCALE, ca[16+2*i+1] * TPSCALE);
    uint4* dst2 = (uint4*)(tp + (size_t)b * N + 4096 + t * 16);
    dst2[0] = pk.q[0]; dst2[1] = pk.q[1];
}

// ---------------- v = nu / (sum of 512 fp16 partials + stab) ----------------
__global__ __launch_bounds__(256) void colfin_kernel(
    const __half* __restrict__ tp, __half* __restrict__ v)
{
    int t = threadIdx.x;
    int c2 = blockIdx.x * 32 + (t & 31);    // half2 column index; grid 128
    int g  = t >> 5;                         // 8 chunk groups
    const __half2* tp2 = (const __half2*)tp;
    float sx = 0.f, sy = 0.f;
    #pragma unroll 4
    for (int k = 0; k < 64; ++k) {
        float2 f = __half22float2(tp2[(size_t)(g * 64 + k) * (N / 2) + c2]);
        sx += f.x; sy += f.y;
    }
    __shared__ float redx[8][33], redy[8][33];
    redx[g][t & 31] = sx; redy[g][t & 31] = sy;
    __syncthreads();
    if (t < 32) {
        float ax = 0.f, ay = 0.f;
        #pragma unroll
        for (int gg = 0; gg < 8; ++gg) { ax += redx[gg][t]; ay += redy[gg][t]; }
        float vx = NU / (ax * TPINV + STABV);
        float vy = NU / (ay * TPINV + STABV);
        ((__half2*)v)[blockIdx.x * 32 + t] = __floats2half2_rn(vx, vy);
    }
}

// ---------------- loss = sum u_i K_ij v_j * (-eps ln K_ij) ----------------
__global__ __launch_bounds__(256) void loss_kernel(
    const unsigned char* __restrict__ Km, const float* __restrict__ u,
    const __half* __restrict__ vv, float* __restrict__ out)
{
    int t = threadIdx.x;
    int j0 = blockIdx.x * 2048 + t * 8;     // grid (4, 128)
    int i0 = blockIdx.y * 64;
    float vj[8];
    {
        const __half2* vp = (const __half2*)(vv + j0);
        #pragma unroll
        for (int i = 0; i < 4; ++i) {
            float2 f = __half22float2(vp[i]);
            vj[2*i] = f.x; vj[2*i+1] = f.y;
        }
    }
    float a[8] = {};
    for (int i = 0; i < 64; ++i) {
        float ui = u[i0 + i];
        uint2 raw = *(const uint2*)(Km + (size_t)(i0 + i) * N + j0);
        float k[8];
        f32x2 lo = __builtin_amdgcn_cvt_pk_f32_fp8((int)raw.x, false);
        f32x2 hi = __builtin_amdgcn_cvt_pk_f32_fp8((int)raw.x, true);
        k[0]=lo[0]; k[1]=lo[1]; k[2]=hi[0]; k[3]=hi[1];
        lo = __builtin_amdgcn_cvt_pk_f32_fp8((int)raw.y, false);
        hi = __builtin_amdgcn_cvt_pk_f32_fp8((int)raw.y, true);
        k[4]=lo[0]; k[5]=lo[1]; k[6]=hi[0]; k[7]=hi[1];
        #pragma unroll
        for (int q = 0; q < 8; ++q) {
            float kk = fmaxf(k[q], 6e-8f);
            a[q] += ui * kk * __log2f(kk);
        }
    }
    float s = 0.f;
    #pragma unroll
    for (int q = 0; q < 8; ++q) s += a[q] * vj[q];
    s *= NEG_EPS_LN2;
    #pragma unroll
    for (int off = 32; off > 0; off >>= 1) s += __shfl_down(s, off, 64);
    __shared__ float ws[4];
    if ((t & 63) == 0) ws[t >> 6] = s;
    __syncthreads();
    if (t == 0) atomicAdd(out, ws[0] + ws[1] + ws[2] + ws[3]);
}

extern "C" void kernel_launch(void* const* d_in, const int* in_sizes, int n_in,
                              void* d_out, int out_size, void* d_ws, size_t ws_size,
                              hipStream_t stream) {
    const float* X = (const float*)d_in[0];
    const float* Y = (const float*)d_in[1];
    float* out = (float*)d_out;

    char* ws = (char*)d_ws;
    unsigned char* Km = (unsigned char*)ws;
    size_t off = (size_t)N * N;                       // 64 MB fp8
    __half* tp = (__half*)(ws + off); off += (size_t)512 * N * sizeof(__half); // 8 MB
    float* x2 = (float*)(ws + off); off += (size_t)N * 4;
    float* y2 = (float*)(ws + off); off += (size_t)N * 4;
    float* u  = (float*)(ws + off); off += (size_t)N * 4;
    __half* v = (__half*)(ws + off); off += (size_t)N * sizeof(__half);

    init_kernel<<<4096, 256, 0, stream>>>(X, Y, x2, y2, v, out);
    kmat_kernel<<<dim3(N / 128, N / 128), 256, 0, stream>>>(X, Y, x2, y2, Km);
    for (int it = 0; it < NITER; ++it) {
        iter_kernel<<<512, 256, 0, stream>>>(Km, v, u, tp);
        colfin_kernel<<<128, 256, 0, stream>>>(tp, v);
    }
    loss_kernel<<<dim3(4, 128), 256, 0, stream>>>(Km, u, v, out);
}